// Round 5
// baseline (80.378 us; speedup 1.0000x reference)
//
#include <hip/hip_runtime.h>

// Geometric product over 3D PGA, 16-component multivectors.
// C[..., k] = sum_ij A[...,i] * B[...,j] * cayley[k,i,j]
// Cayley table rebuilt at COMPILE TIME (mirrors the reference Python); the
// 16x16 double loop constant-folds to the 192 nonzero +-1 fp32 FMAs.
//
// R5: kill the barriers. The AoS transpose only needs intra-wave exchange,
// so each wave gets a PRIVATE 8KB LDS slice (its own 64 MVs of A and B).
// ds_write -> ds_read ordering within a wave is guaranteed by lgkmcnt (the
// compiler inserts the waits); no __syncthreads anywhere, so waves never
// park at block-wide vmcnt(0) drains (R4: occupancy 36%, both pipes idle).
// Output skips LDS entirely: 4 strided dwordx4 stores per thread write the
// thread's full contiguous 64B, which L2 merges to full lines.
// LDS swizzle slot(m,q) = m*16 + ((q^((m>>1)&3))<<2) is conflict-free for
// both the staging and compute patterns (verified by enumeration, R4).

namespace {

struct CayleyLUT {
    int idx[16][16];
    int sgn[16][16];
};

constexpr CayleyLUT make_lut() {
    CayleyLUT L{};
    constexpr int MASK[16] = {0, 2, 4, 8, 1, 6, 10, 12, 3, 5, 9, 14, 7, 11, 13, 15};
    constexpr int SIGN[16] = {1, 1, 1, 1, 1, 1, 1, 1, -1, -1, -1, 1, 1, 1, 1, -1};
    for (int i = 0; i < 16; ++i) {
        for (int j = 0; j < 16; ++j) {
            L.idx[i][j] = 0;
            L.sgn[i][j] = 0;
            if (MASK[i] & MASK[j] & 1) continue;  // shared null e0 -> vanishes
            const int rm = MASK[i] ^ MASK[j];
            int k = 0;
            for (int t = 0; t < 16; ++t)
                if (MASK[t] == rm) k = t;
            int s = 1;
            for (int bit = 0; bit < 4; ++bit) {
                if ((MASK[i] >> bit) & 1) {
                    int lower = MASK[j] & ((1 << bit) - 1);
                    int c = 0;
                    for (int x = lower; x; x >>= 1) c += x & 1;
                    if (c & 1) s = -s;
                }
            }
            L.idx[i][j] = k;
            L.sgn[i][j] = SIGN[i] * SIGN[j] * s * SIGN[k];
        }
    }
    return L;
}

constexpr CayleyLUT LUT = make_lut();

__device__ __forceinline__ int slot(int m, int q) {
    // Float offset of quad q of MV m in a wave's swizzled LDS slice.
    return m * 16 + ((q ^ ((m >> 1) & 3)) << 2);
}

__device__ __forceinline__ void gp_compute(const float* a, const float* b, float* c) {
#pragma unroll
    for (int k = 0; k < 16; ++k) c[k] = 0.0f;
#pragma unroll
    for (int i = 0; i < 16; ++i) {
#pragma unroll
        for (int j = 0; j < 16; ++j) {
            const int s = LUT.sgn[i][j];
            if (s != 0) {
                const int k = LUT.idx[i][j];
                c[k] = fmaf(s > 0 ? a[i] : -a[i], b[j], c[k]);
            }
        }
    }
}

__global__ __launch_bounds__(256) void gp_kernel(const float* __restrict__ A,
                                                 const float* __restrict__ B,
                                                 float* __restrict__ C,
                                                 long long n_mv) {
    __shared__ float sA[4][64 * 16];  // 16 KiB: one 4KB slice per wave
    __shared__ float sB[4][64 * 16];  // 16 KiB
    const int tid = threadIdx.x;
    const int wid = tid >> 6;
    const int lane = tid & 63;
    float* __restrict__ wA = sA[wid];
    float* __restrict__ wB = sB[wid];

    const long long wave_mv = (long long)blockIdx.x * 256 + (long long)(wid << 6);
    if (wave_mv >= n_mv) return;  // whole-wave uniform; no barriers in kernel
    const long long rem = n_mv - wave_mv;

    const float4* __restrict__ A4 = reinterpret_cast<const float4*>(A) + (wave_mv << 2);
    const float4* __restrict__ B4 = reinterpret_cast<const float4*>(B) + (wave_mv << 2);
    float4* __restrict__ C4 = reinterpret_cast<float4*>(C) + (wave_mv << 2);

    if (rem >= 64) {
        // ---- stage in: coalesced float4 loads, swizzled scatter into the
        //      wave's private slice (ordering via lgkmcnt only) ----
#pragma unroll
        for (int r = 0; r < 4; ++r) {
            const int f = (r << 6) + lane;
            const float4 va = A4[f];
            const float4 vb = B4[f];
            const int o = slot(f >> 2, f & 3);
            *reinterpret_cast<float4*>(&wA[o]) = va;
            *reinterpret_cast<float4*>(&wB[o]) = vb;
        }
        // ---- compute: lane l owns MV l of the wave's 64 ----
        float a[16], b[16];
#pragma unroll
        for (int q = 0; q < 4; ++q) {
            const int o = slot(lane, q);
            const float4 va = *reinterpret_cast<const float4*>(&wA[o]);
            const float4 vb = *reinterpret_cast<const float4*>(&wB[o]);
            a[4 * q + 0] = va.x; a[4 * q + 1] = va.y; a[4 * q + 2] = va.z; a[4 * q + 3] = va.w;
            b[4 * q + 0] = vb.x; b[4 * q + 1] = vb.y; b[4 * q + 2] = vb.z; b[4 * q + 3] = vb.w;
        }
        float c[16];
        gp_compute(a, b, c);
        // ---- direct stores: 4 dwordx4 at 64B lane stride; each thread
        //      writes its full 64B so L2 merges to whole lines ----
#pragma unroll
        for (int q = 0; q < 4; ++q) {
            float4 v;
            v.x = c[4 * q + 0]; v.y = c[4 * q + 1]; v.z = c[4 * q + 2]; v.w = c[4 * q + 3];
            C4[(lane << 2) + q] = v;
        }
    } else {
        // ---- tail wave: per-access guards ----
        const int nf4 = (int)(rem << 2);
#pragma unroll
        for (int r = 0; r < 4; ++r) {
            const int f = (r << 6) + lane;
            if (f < nf4) {
                const float4 va = A4[f];
                const float4 vb = B4[f];
                const int o = slot(f >> 2, f & 3);
                *reinterpret_cast<float4*>(&wA[o]) = va;
                *reinterpret_cast<float4*>(&wB[o]) = vb;
            }
        }
        if (lane < (int)rem) {
            float a[16], b[16];
#pragma unroll
            for (int q = 0; q < 4; ++q) {
                const int o = slot(lane, q);
                const float4 va = *reinterpret_cast<const float4*>(&wA[o]);
                const float4 vb = *reinterpret_cast<const float4*>(&wB[o]);
                a[4 * q + 0] = va.x; a[4 * q + 1] = va.y; a[4 * q + 2] = va.z; a[4 * q + 3] = va.w;
                b[4 * q + 0] = vb.x; b[4 * q + 1] = vb.y; b[4 * q + 2] = vb.z; b[4 * q + 3] = vb.w;
            }
            float c[16];
            gp_compute(a, b, c);
#pragma unroll
            for (int q = 0; q < 4; ++q) {
                float4 v;
                v.x = c[4 * q + 0]; v.y = c[4 * q + 1]; v.z = c[4 * q + 2]; v.w = c[4 * q + 3];
                C4[(lane << 2) + q] = v;
            }
        }
    }
}

}  // namespace

extern "C" void kernel_launch(void* const* d_in, const int* in_sizes, int n_in,
                              void* d_out, int out_size, void* d_ws, size_t ws_size,
                              hipStream_t stream) {
    const float* A = (const float*)d_in[0];
    const float* B = (const float*)d_in[1];
    float* C = (float*)d_out;
    const long long n_mv = (long long)in_sizes[0] / 16;
    const int nblocks = (int)((n_mv + 255) / 256);
    gp_kernel<<<nblocks, 256, 0, stream>>>(A, B, C, n_mv);
}

// Round 7
// 62.176 us; speedup vs baseline: 1.2928x; 1.2928x over previous
//
#include <hip/hip_runtime.h>

// Geometric product over 3D PGA, 16-component multivectors.
// C[..., k] = sum_ij A[...,i] * B[...,j] * cayley[k,i,j]
// Cayley table rebuilt at COMPILE TIME (mirrors the reference Python); the
// 16x16 double loop constant-folds to the 192 nonzero +-1 fp32 FMAs.
//
// R7 = R6 with the compile fix: __builtin_nontemporal_store needs a native
// clang vector type, not HIP_vector_type. Theory unchanged: measured
// FETCH_SIZE is exactly one input's worth (134MB) -> L3 already serves half
// the A+B re-reads across graph replays; the C writeback (134MB, never read)
// evicts the rest. 'nt' stores keep C out of L2/L3 so A+B (268MB) mostly
// fits the 256MB L3 -> FETCH collapses, HBM traffic 268->~160MB.
// (R5 lesson: keep ALL global I/O coalesced; barriers are not the limiter.)

namespace {

typedef float f32x4 __attribute__((ext_vector_type(4)));

struct CayleyLUT {
    int idx[16][16];
    int sgn[16][16];
};

constexpr CayleyLUT make_lut() {
    CayleyLUT L{};
    constexpr int MASK[16] = {0, 2, 4, 8, 1, 6, 10, 12, 3, 5, 9, 14, 7, 11, 13, 15};
    constexpr int SIGN[16] = {1, 1, 1, 1, 1, 1, 1, 1, -1, -1, -1, 1, 1, 1, 1, -1};
    for (int i = 0; i < 16; ++i) {
        for (int j = 0; j < 16; ++j) {
            L.idx[i][j] = 0;
            L.sgn[i][j] = 0;
            if (MASK[i] & MASK[j] & 1) continue;  // shared null e0 -> vanishes
            const int rm = MASK[i] ^ MASK[j];
            int k = 0;
            for (int t = 0; t < 16; ++t)
                if (MASK[t] == rm) k = t;
            int s = 1;
            for (int bit = 0; bit < 4; ++bit) {
                if ((MASK[i] >> bit) & 1) {
                    int lower = MASK[j] & ((1 << bit) - 1);
                    int c = 0;
                    for (int x = lower; x; x >>= 1) c += x & 1;
                    if (c & 1) s = -s;
                }
            }
            L.idx[i][j] = k;
            L.sgn[i][j] = SIGN[i] * SIGN[j] * s * SIGN[k];
        }
    }
    return L;
}

constexpr CayleyLUT LUT = make_lut();

__device__ __forceinline__ int slot(int m, int q) {
    // Float offset of quad q of MV m in the swizzled LDS tile.
    // Conflict-free for both the staging (m=f>>2,q=f&3) and compute
    // (m=lane, q fixed) patterns — enumerated in R4.
    return m * 16 + ((q ^ ((m >> 1) & 3)) << 2);
}

__device__ __forceinline__ void gp_compute(const float* a, const float* b, float* c) {
#pragma unroll
    for (int k = 0; k < 16; ++k) c[k] = 0.0f;
#pragma unroll
    for (int i = 0; i < 16; ++i) {
#pragma unroll
        for (int j = 0; j < 16; ++j) {
            const int s = LUT.sgn[i][j];
            if (s != 0) {
                const int k = LUT.idx[i][j];
                c[k] = fmaf(s > 0 ? a[i] : -a[i], b[j], c[k]);
            }
        }
    }
}

__global__ __launch_bounds__(256) void gp_kernel(const float* __restrict__ A,
                                                 const float* __restrict__ B,
                                                 float* __restrict__ C,
                                                 long long n_mv) {
    __shared__ float sA[256 * 16];  // 16 KiB
    __shared__ float sB[256 * 16];  // 16 KiB
    const int t = threadIdx.x;
    const long long base_mv = (long long)blockIdx.x * 256;
    const bool full = (base_mv + 256 <= n_mv);
    const int mv_here = full ? 256 : (int)(n_mv - base_mv);
    const int nf4 = mv_here * 4;

    const f32x4* __restrict__ A4 = reinterpret_cast<const f32x4*>(A) + base_mv * 4;
    const f32x4* __restrict__ B4 = reinterpret_cast<const f32x4*>(B) + base_mv * 4;
    f32x4* __restrict__ C4 = reinterpret_cast<f32x4*>(C) + base_mv * 4;

    // ---- stage in (coalesced 16B loads, swizzled LDS scatter) ----
    if (full) {
#pragma unroll
        for (int r = 0; r < 4; ++r) {
            const int f = t + 256 * r;
            const f32x4 va = A4[f];
            const f32x4 vb = B4[f];
            const int o = slot(f >> 2, f & 3);
            *reinterpret_cast<f32x4*>(&sA[o]) = va;
            *reinterpret_cast<f32x4*>(&sB[o]) = vb;
        }
    } else {
#pragma unroll
        for (int r = 0; r < 4; ++r) {
            const int f = t + 256 * r;
            if (f < nf4) {
                const f32x4 va = A4[f];
                const f32x4 vb = B4[f];
                const int o = slot(f >> 2, f & 3);
                *reinterpret_cast<f32x4*>(&sA[o]) = va;
                *reinterpret_cast<f32x4*>(&sB[o]) = vb;
            }
        }
    }
    __syncthreads();

    // ---- compute: thread t owns MV t of the tile ----
    if (full || t < mv_here) {
        float a[16], b[16];
#pragma unroll
        for (int q = 0; q < 4; ++q) {
            const int o = slot(t, q);
            const f32x4 va = *reinterpret_cast<const f32x4*>(&sA[o]);
            const f32x4 vb = *reinterpret_cast<const f32x4*>(&sB[o]);
            a[4 * q + 0] = va.x; a[4 * q + 1] = va.y; a[4 * q + 2] = va.z; a[4 * q + 3] = va.w;
            b[4 * q + 0] = vb.x; b[4 * q + 1] = vb.y; b[4 * q + 2] = vb.z; b[4 * q + 3] = vb.w;
        }
        float c[16];
        gp_compute(a, b, c);
        // Stage out into sA: thread t only touches row t (its own compute
        // input), so no barrier needed before these writes.
#pragma unroll
        for (int q = 0; q < 4; ++q) {
            f32x4 v;
            v.x = c[4 * q + 0]; v.y = c[4 * q + 1]; v.z = c[4 * q + 2]; v.w = c[4 * q + 3];
            *reinterpret_cast<f32x4*>(&sA[slot(t, q)]) = v;
        }
    }
    __syncthreads();

    // ---- stage out (swizzled LDS gather, coalesced NONTEMPORAL stores) ----
    if (full) {
#pragma unroll
        for (int r = 0; r < 4; ++r) {
            const int f = t + 256 * r;
            const f32x4 v = *reinterpret_cast<const f32x4*>(&sA[slot(f >> 2, f & 3)]);
            __builtin_nontemporal_store(v, &C4[f]);
        }
    } else {
#pragma unroll
        for (int r = 0; r < 4; ++r) {
            const int f = t + 256 * r;
            if (f < nf4) {
                const f32x4 v = *reinterpret_cast<const f32x4*>(&sA[slot(f >> 2, f & 3)]);
                __builtin_nontemporal_store(v, &C4[f]);
            }
        }
    }
}

}  // namespace

extern "C" void kernel_launch(void* const* d_in, const int* in_sizes, int n_in,
                              void* d_out, int out_size, void* d_ws, size_t ws_size,
                              hipStream_t stream) {
    const float* A = (const float*)d_in[0];
    const float* B = (const float*)d_in[1];
    float* C = (float*)d_out;
    const long long n_mv = (long long)in_sizes[0] / 16;
    const int nblocks = (int)((n_mv + 255) / 256);
    gp_kernel<<<nblocks, 256, 0, stream>>>(A, B, C, n_mv);
}